// Round 19
// baseline (200.819 us; speedup 1.0000x reference)
//
#include <hip/hip_runtime.h>

// ---------------------------------------------------------------------------
// GIN forward, bf16 node features. Padded-bucket CSR build + FUSED
// aggregate+MFMA-MLP layers (512-thr / 8-wave blocks, 23KB LDS, 4 blk/CU;
// gather walks FOUR nodes per wave concurrently, 32 rows in flight) +
// tiny readout.
// d_out layout: [out (G*64) | h (N*64)]
// ws: [xb | Z0b | rstart | rend | cnts | ebuf | hg]
// Bucket = dst >> 7.  Requires N < 65536 (ids pack u16).
// ---------------------------------------------------------------------------

#define EPB 2048
#define PER 32
#define MAXB 512
#define NBP 512

typedef __attribute__((ext_vector_type(8))) short short8;
typedef __attribute__((ext_vector_type(4))) float f32x4;

__device__ __forceinline__ unsigned bf16pack(float a, float b) {
    unsigned ua = __float_as_uint(a);
    unsigned ub = __float_as_uint(b);
    ua = (ua + 0x7FFFu + ((ua >> 16) & 1u)) >> 16;
    ub = (ub + 0x7FFFu + ((ub >> 16) & 1u)) & 0xFFFF0000u;
    return ua | ub;
}
__device__ __forceinline__ unsigned short bf16r(float a) {
    unsigned u = __float_as_uint(a);
    return (unsigned short)((u + 0x7FFFu + ((u >> 16) & 1u)) >> 16);
}
__device__ __forceinline__ float bf16lo(unsigned w) { return __uint_as_float(w << 16); }
__device__ __forceinline__ float bf16hi(unsigned w) { return __uint_as_float(w & 0xFFFF0000u); }

#define ACC8(A, V)                                       \
    A[0] += bf16lo((V).x); A[1] += bf16hi((V).x);        \
    A[2] += bf16lo((V).y); A[3] += bf16hi((V).y);        \
    A[4] += bf16lo((V).z); A[5] += bf16hi((V).z);        \
    A[6] += bf16lo((V).w); A[7] += bf16hi((V).w);

// ---- K1: cast x->bf16 (grid-strided) + padded-bucket scatter ---------------
__global__ __launch_bounds__(256) void cast_scatter(
    uint4* __restrict__ xb4, const float4* __restrict__ x4, int nq,
    unsigned* __restrict__ ebuf, int* __restrict__ cnts,
    const int* __restrict__ src, const int* __restrict__ dst,
    int E, int NB, int CAPB) {
    __shared__ int h[MAXB];
    const int t = threadIdx.x;
    const int b = blockIdx.x;
    const int nblk = gridDim.x;

    for (int i = b * 256 + t; i < nq; i += nblk * 256) {
        float4 a = x4[2 * i], c = x4[2 * i + 1];
        uint4 o;
        o.x = bf16pack(a.x, a.y); o.y = bf16pack(a.z, a.w);
        o.z = bf16pack(c.x, c.y); o.w = bf16pack(c.z, c.w);
        xb4[i] = o;
    }

    for (int i = t; i < MAXB; i += 256) h[i] = 0;
    __syncthreads();

    const int base = b * EPB;
#pragma unroll
    for (int i = 0; i < 8; ++i) {
        int e = base + i * 256 + t;
        if (e < E) {
            int s = src[e];
            int d = dst[e];
            int k = d >> 7;
            int p = atomicAdd(&h[k], 1);
            if (p < PER)
                ebuf[(size_t)k * CAPB + b * PER + p] =
                    ((unsigned)s << 16) | (unsigned)d;
        }
    }
    __syncthreads();
    for (int i = t; i < NB; i += 256) cnts[(size_t)b * NBP + i] = min(h[i], PER);
}

// ---- K2: compact bucket, rstart/rend + col; also zeroes hg -----------------
__global__ __launch_bounds__(256) void bucket_fill2(
    unsigned* __restrict__ ebuf, const int* __restrict__ cnts,
    int* __restrict__ rstart, int* __restrict__ rend,
    float* __restrict__ hg, int hgn,
    int N, int EB, int NB, int CAPB) {
    __shared__ int tbase[256];
    __shared__ unsigned pairLDS[4608];
    __shared__ unsigned colLDS[4608];
    __shared__ int deg[128], off[128], cur[128];
    const int bb = blockIdx.x;
    const int t = threadIdx.x;
    const int nb0 = bb << 7;
    const int CPT = (EB + 255) / 256;

    for (int i = bb * 256 + t; i < hgn; i += NB * 256) hg[i] = 0.f;

    int myc[8];
    int s = 0;
#pragma unroll 4
    for (int k = 0; k < CPT; ++k) {
        int c = t * CPT + k;
        int v = (c < EB) ? cnts[(size_t)c * NBP + bb] : 0;
        myc[k] = v;
        s += v;
    }
    tbase[t] = s;
    __syncthreads();
    for (int o = 1; o < 256; o <<= 1) {
        int u = (t >= o) ? tbase[t - o] : 0;
        __syncthreads();
        tbase[t] += u;
        __syncthreads();
    }
    const int m = tbase[255];
    int wbase = (t > 0) ? tbase[t - 1] : 0;

#pragma unroll 4
    for (int k = 0; k < CPT; ++k) {
        int c = t * CPT + k;
        int cnt = myc[k];
        for (int j = 0; j < cnt; ++j)
            pairLDS[wbase + j] = ebuf[(size_t)bb * CAPB + c * PER + j];
        wbase += cnt;
    }

    if (t < 128) deg[t] = 0;
    __syncthreads();

    for (int k = t; k < m; k += 256)
        atomicAdd(&deg[(int)(pairLDS[k] & 0xFFFFu) - nb0], 1);
    __syncthreads();
    if (t < 128) off[t] = deg[t];
    __syncthreads();
    for (int s2 = 1; s2 < 128; s2 <<= 1) {
        int u = 0;
        if (t < 128 && t >= s2) u = off[t - s2];
        __syncthreads();
        if (t < 128) off[t] += u;
        __syncthreads();
    }
    if (t < 128) {
        int excl = off[t] - deg[t];
        cur[t] = excl;
        int node = nb0 + t;
        if (node < N) {
            rstart[node] = bb * CAPB + excl;
            rend[node] = bb * CAPB + excl + deg[t];
        }
    }
    __syncthreads();
    for (int k = t; k < m; k += 256) {
        unsigned v = pairLDS[k];
        int dl = (int)(v & 0xFFFFu) - nb0;
        int p = atomicAdd(&cur[dl], 1);
        colLDS[p] = v >> 16;
    }
    __syncthreads();
    for (int k = t; k < m; k += 256) ebuf[(size_t)bb * CAPB + k] = colLDS[k];
}

// ---- FUSED GIN layer: quad-node interleaved gather + MFMA MLP -------------
// 512 threads = 8 waves; block covers 32 rows. Each wave processes its 4
// rows concurrently (32 neighbor rows / 8KB in flight). MFMA: wave w
// computes tile (tr=w>>2, tc=w&3), K=64. TWO adds GEMM2; !TWO accumulates
// per-graph sums into hg.
template <bool TWO, bool OUTB>
__global__ __launch_bounds__(512, 8) void gin_layer(
    const unsigned* __restrict__ inb, unsigned* __restrict__ outb,
    float* __restrict__ outf,
    const int* __restrict__ rstart, const int* __restrict__ rend,
    const unsigned* __restrict__ col, const float* __restrict__ eps, int N,
    const float* __restrict__ Wa, const float* __restrict__ ba,
    const float* __restrict__ Wb, const float* __restrict__ bb,
    const float* __restrict__ gi, const float* __restrict__ bei,
    const float* __restrict__ mi, const float* __restrict__ vi,
    const float* __restrict__ go, const float* __restrict__ beo,
    const float* __restrict__ mo, const float* __restrict__ vo,
    const int* __restrict__ gid, float* __restrict__ hg) {
    constexpr int PB = 72;
    __shared__ __align__(16) unsigned short XY[32 * PB];
    __shared__ __align__(16) unsigned short W1t[64 * PB];
    __shared__ __align__(16) unsigned short W2t[TWO ? 64 * PB : 8];
    __shared__ float Yf[TWO ? 1 : 32 * 68];
    __shared__ int gidl[TWO ? 1 : 32];

    const int t = threadIdx.x;
    const int row0 = blockIdx.x * 32;
    const int lane = t & 63;
    const int w = t >> 6;

    // ---- stage weights (f32 [k][c] -> Wt[c][k] bf16) ----
    for (int p = t; p < 1024; p += 512) {
        int k = p >> 4, c4 = (p & 15) * 4;
        float4 v = *reinterpret_cast<const float4*>(&Wa[k * 64 + c4]);
        W1t[(c4 + 0) * PB + k] = bf16r(v.x);
        W1t[(c4 + 1) * PB + k] = bf16r(v.y);
        W1t[(c4 + 2) * PB + k] = bf16r(v.z);
        W1t[(c4 + 3) * PB + k] = bf16r(v.w);
        if (TWO) {
            float4 u = *reinterpret_cast<const float4*>(&Wb[k * 64 + c4]);
            W2t[(c4 + 0) * PB + k] = bf16r(u.x);
            W2t[(c4 + 1) * PB + k] = bf16r(u.y);
            W2t[(c4 + 2) * PB + k] = bf16r(u.z);
            W2t[(c4 + 3) * PB + k] = bf16r(u.w);
        }
    }
    if (!TWO && t < 32) gidl[t] = (row0 + t < N) ? gid[row0 + t] : -1;

    // ---- quad-node interleaved gather-aggregate, bf16 -> XY ----
    {
        const int q = lane & 7;
        const int jj = lane >> 3;
        const uint4* in4 = reinterpret_cast<const uint4*>(inb);
        const float s = 1.0f + eps[0];
        const int r0 = w * 4, r1 = r0 + 1, r2 = r0 + 2, r3 = r0 + 3;
        const int n0 = row0 + r0, n1 = row0 + r1, n2 = row0 + r2, n3 = row0 + r3;
        float a0[8], a1[8], a2[8], a3[8];
#pragma unroll
        for (int k2 = 0; k2 < 8; ++k2) {
            a0[k2] = 0.f; a1[k2] = 0.f; a2[k2] = 0.f; a3[k2] = 0.f;
        }
        int j0 = 0, e0 = 0, j1 = 0, e1 = 0, j2 = 0, e2 = 0, j3 = 0, e3 = 0;
        if (n0 < N) { j0 = rstart[n0]; e0 = rend[n0]; }
        if (n1 < N) { j1 = rstart[n1]; e1 = rend[n1]; }
        if (n2 < N) { j2 = rstart[n2]; e2 = rend[n2]; }
        if (n3 < N) { j3 = rstart[n3]; e3 = rend[n3]; }

        // 4-way interleaved main loop: 32 neighbor rows in flight
        while (j0 + 8 <= e0 && j1 + 8 <= e1 && j2 + 8 <= e2 && j3 + 8 <= e3) {
            unsigned c0 = col[j0 + jj];
            unsigned c1 = col[j1 + jj];
            unsigned c2 = col[j2 + jj];
            unsigned c3 = col[j3 + jj];
            uint4 v0 = in4[(size_t)c0 * 8 + q];
            uint4 v1 = in4[(size_t)c1 * 8 + q];
            uint4 v2 = in4[(size_t)c2 * 8 + q];
            uint4 v3 = in4[(size_t)c3 * 8 + q];
            ACC8(a0, v0)
            ACC8(a1, v1)
            ACC8(a2, v2)
            ACC8(a3, v3)
            j0 += 8; j1 += 8; j2 += 8; j3 += 8;
        }
        // pairwise drains
        while (j0 + 8 <= e0 && j1 + 8 <= e1) {
            unsigned c0 = col[j0 + jj];
            unsigned c1 = col[j1 + jj];
            uint4 v0 = in4[(size_t)c0 * 8 + q];
            uint4 v1 = in4[(size_t)c1 * 8 + q];
            ACC8(a0, v0)
            ACC8(a1, v1)
            j0 += 8; j1 += 8;
        }
        while (j2 + 8 <= e2 && j3 + 8 <= e3) {
            unsigned c2 = col[j2 + jj];
            unsigned c3 = col[j3 + jj];
            uint4 v2 = in4[(size_t)c2 * 8 + q];
            uint4 v3 = in4[(size_t)c3 * 8 + q];
            ACC8(a2, v2)
            ACC8(a3, v3)
            j2 += 8; j3 += 8;
        }
        while (j0 + 8 <= e0) {
            unsigned c0 = col[j0 + jj];
            uint4 v0 = in4[(size_t)c0 * 8 + q];
            ACC8(a0, v0)
            j0 += 8;
        }
        while (j1 + 8 <= e1) {
            unsigned c1 = col[j1 + jj];
            uint4 v1 = in4[(size_t)c1 * 8 + q];
            ACC8(a1, v1)
            j1 += 8;
        }
        while (j2 + 8 <= e2) {
            unsigned c2 = col[j2 + jj];
            uint4 v2 = in4[(size_t)c2 * 8 + q];
            ACC8(a2, v2)
            j2 += 8;
        }
        while (j3 + 8 <= e3) {
            unsigned c3 = col[j3 + jj];
            uint4 v3 = in4[(size_t)c3 * 8 + q];
            ACC8(a3, v3)
            j3 += 8;
        }
        if (j0 + jj < e0) {
            unsigned c0 = col[j0 + jj];
            uint4 v0 = in4[(size_t)c0 * 8 + q];
            ACC8(a0, v0)
        }
        if (j1 + jj < e1) {
            unsigned c1 = col[j1 + jj];
            uint4 v1 = in4[(size_t)c1 * 8 + q];
            ACC8(a1, v1)
        }
        if (j2 + jj < e2) {
            unsigned c2 = col[j2 + jj];
            uint4 v2 = in4[(size_t)c2 * 8 + q];
            ACC8(a2, v2)
        }
        if (j3 + jj < e3) {
            unsigned c3 = col[j3 + jj];
            uint4 v3 = in4[(size_t)c3 * 8 + q];
            ACC8(a3, v3)
        }

#pragma unroll
        for (int k2 = 0; k2 < 8; ++k2) {
            a0[k2] += __shfl_xor(a0[k2], 8);
            a1[k2] += __shfl_xor(a1[k2], 8);
            a2[k2] += __shfl_xor(a2[k2], 8);
            a3[k2] += __shfl_xor(a3[k2], 8);
            a0[k2] += __shfl_xor(a0[k2], 16);
            a1[k2] += __shfl_xor(a1[k2], 16);
            a2[k2] += __shfl_xor(a2[k2], 16);
            a3[k2] += __shfl_xor(a3[k2], 16);
            a0[k2] += __shfl_xor(a0[k2], 32);
            a1[k2] += __shfl_xor(a1[k2], 32);
            a2[k2] += __shfl_xor(a2[k2], 32);
            a3[k2] += __shfl_xor(a3[k2], 32);
        }
        if (jj == 0) {
            uint4 wv;
            if (n0 < N) {
                uint4 o = in4[(size_t)n0 * 8 + q];
                a0[0] = fmaf(s, bf16lo(o.x), a0[0]);
                a0[1] = fmaf(s, bf16hi(o.x), a0[1]);
                a0[2] = fmaf(s, bf16lo(o.y), a0[2]);
                a0[3] = fmaf(s, bf16hi(o.y), a0[3]);
                a0[4] = fmaf(s, bf16lo(o.z), a0[4]);
                a0[5] = fmaf(s, bf16hi(o.z), a0[5]);
                a0[6] = fmaf(s, bf16lo(o.w), a0[6]);
                a0[7] = fmaf(s, bf16hi(o.w), a0[7]);
            }
            wv.x = bf16pack(a0[0], a0[1]); wv.y = bf16pack(a0[2], a0[3]);
            wv.z = bf16pack(a0[4], a0[5]); wv.w = bf16pack(a0[6], a0[7]);
            *reinterpret_cast<uint4*>(&XY[r0 * PB + q * 8]) = wv;
            if (n1 < N) {
                uint4 o = in4[(size_t)n1 * 8 + q];
                a1[0] = fmaf(s, bf16lo(o.x), a1[0]);
                a1[1] = fmaf(s, bf16hi(o.x), a1[1]);
                a1[2] = fmaf(s, bf16lo(o.y), a1[2]);
                a1[3] = fmaf(s, bf16hi(o.y), a1[3]);
                a1[4] = fmaf(s, bf16lo(o.z), a1[4]);
                a1[5] = fmaf(s, bf16hi(o.z), a1[5]);
                a1[6] = fmaf(s, bf16lo(o.w), a1[6]);
                a1[7] = fmaf(s, bf16hi(o.w), a1[7]);
            }
            wv.x = bf16pack(a1[0], a1[1]); wv.y = bf16pack(a1[2], a1[3]);
            wv.z = bf16pack(a1[4], a1[5]); wv.w = bf16pack(a1[6], a1[7]);
            *reinterpret_cast<uint4*>(&XY[r1 * PB + q * 8]) = wv;
            if (n2 < N) {
                uint4 o = in4[(size_t)n2 * 8 + q];
                a2[0] = fmaf(s, bf16lo(o.x), a2[0]);
                a2[1] = fmaf(s, bf16hi(o.x), a2[1]);
                a2[2] = fmaf(s, bf16lo(o.y), a2[2]);
                a2[3] = fmaf(s, bf16hi(o.y), a2[3]);
                a2[4] = fmaf(s, bf16lo(o.z), a2[4]);
                a2[5] = fmaf(s, bf16hi(o.z), a2[5]);
                a2[6] = fmaf(s, bf16lo(o.w), a2[6]);
                a2[7] = fmaf(s, bf16hi(o.w), a2[7]);
            }
            wv.x = bf16pack(a2[0], a2[1]); wv.y = bf16pack(a2[2], a2[3]);
            wv.z = bf16pack(a2[4], a2[5]); wv.w = bf16pack(a2[6], a2[7]);
            *reinterpret_cast<uint4*>(&XY[r2 * PB + q * 8]) = wv;
            if (n3 < N) {
                uint4 o = in4[(size_t)n3 * 8 + q];
                a3[0] = fmaf(s, bf16lo(o.x), a3[0]);
                a3[1] = fmaf(s, bf16hi(o.x), a3[1]);
                a3[2] = fmaf(s, bf16lo(o.y), a3[2]);
                a3[3] = fmaf(s, bf16hi(o.y), a3[3]);
                a3[4] = fmaf(s, bf16lo(o.z), a3[4]);
                a3[5] = fmaf(s, bf16hi(o.z), a3[5]);
                a3[6] = fmaf(s, bf16lo(o.w), a3[6]);
                a3[7] = fmaf(s, bf16hi(o.w), a3[7]);
            }
            wv.x = bf16pack(a3[0], a3[1]); wv.y = bf16pack(a3[2], a3[3]);
            wv.z = bf16pack(a3[4], a3[5]); wv.w = bf16pack(a3[6], a3[7]);
            *reinterpret_cast<uint4*>(&XY[r3 * PB + q * 8]) = wv;
        }
    }
    __syncthreads();

    // ---- GEMM1: wave w -> tile (tr=w>>2, tc=w&3) ----
    const int cl = lane & 15;
    const int kg = lane >> 4;
    const int tr = w >> 2;
    const int tc = w & 3;
    const int arow = tr * 16 + cl;
    const int bcol = tc * 16 + cl;
    const int rowb = tr * 16 + kg * 4;
    const int c = tc * 16 + cl;

    f32x4 acc = (f32x4){0.f, 0.f, 0.f, 0.f};
#pragma unroll
    for (int kk = 0; kk < 64; kk += 32) {
        short8 af = *reinterpret_cast<const short8*>(&XY[arow * PB + kk + kg * 8]);
        short8 bf = *reinterpret_cast<const short8*>(&W1t[bcol * PB + kk + kg * 8]);
        acc = __builtin_amdgcn_mfma_f32_16x16x32_bf16(af, bf, acc, 0, 0, 0);
    }

    if (TWO) {
        __syncthreads();
        {
            float bias = ba[c];
#pragma unroll
            for (int r = 0; r < 4; ++r)
                XY[(rowb + r) * PB + c] = bf16r(fmaxf(acc[r] + bias, 0.f));
        }
        __syncthreads();
        acc = (f32x4){0.f, 0.f, 0.f, 0.f};
#pragma unroll
        for (int kk = 0; kk < 64; kk += 32) {
            short8 af = *reinterpret_cast<const short8*>(&XY[arow * PB + kk + kg * 8]);
            short8 bf = *reinterpret_cast<const short8*>(&W2t[bcol * PB + kk + kg * 8]);
            acc = __builtin_amdgcn_mfma_f32_16x16x32_bf16(af, bf, acc, 0, 0, 0);
        }
    }

    // ---- epilogue: bias + relu + fused double-BN + relu + store ----
    {
        const float* bias2 = TWO ? bb : ba;
        float si = gi[c] * rsqrtf(vi[c] + 1e-5f);
        float ti = bei[c] - mi[c] * si;
        float so = go[c] * rsqrtf(vo[c] + 1e-5f);
        float to = beo[c] - mo[c] * so;
        float scv = si * so;
        float shv = ti * so + to;
        float bias = bias2[c];
#pragma unroll
        for (int r = 0; r < 4; ++r) {
            int grow = row0 + rowb + r;
            float y = 0.f;
            if (grow < N) {
                float u = fmaxf(acc[r] + bias, 0.f);
                y = fmaxf(u * scv + shv, 0.f);
                if (OUTB) {
                    reinterpret_cast<unsigned short*>(outb)[(size_t)grow * 64 + c] =
                        bf16r(y);
                } else {
                    outf[(size_t)grow * 64 + c] = y;
                }
            }
            if (!TWO) Yf[(rowb + r) * 68 + c] = y;
        }
    }

    if (!TWO) {
        __syncthreads();
        if (t < 64) {
            const int cc = t;
            float run = 0.f;
            int cg = -2;
            for (int r = 0; r < 32; ++r) {
                int rg = gidl[r];
                if (rg != cg) {
                    if (cg >= 0) atomicAdd(&hg[(size_t)cg * 64 + cc], run);
                    run = 0.f;
                    cg = rg;
                }
                if (rg >= 0) run += Yf[r * 68 + cc];
            }
            if (cg >= 0) atomicAdd(&hg[(size_t)cg * 64 + cc], run);
        }
    }
}

__device__ __forceinline__ int lbound(const int* __restrict__ a, int n, int v) {
    int lo = 0, hi = n;
    while (lo < hi) {
        int mid = (lo + hi) >> 1;
        if (a[mid] < v) lo = mid + 1;
        else hi = mid;
    }
    return lo;
}

// ---- tiny readout: out = relu(hg/cnt @ W1 + b1) @ W2 + b2 ------------------
__global__ __launch_bounds__(64) void readout_small(
    const float* __restrict__ hg, const int* __restrict__ gid, int N,
    const float* __restrict__ W1, const float* __restrict__ b1,
    const float* __restrict__ W2, const float* __restrict__ b2,
    float* __restrict__ out) {
    __shared__ float hgl[64];
    __shared__ float t1[64];
    const int g = blockIdx.x;
    const int c = threadIdx.x;

    const int lo = lbound(gid, N, g);
    const int hi = lbound(gid, N, g + 1);
    hgl[c] = hg[(size_t)g * 64 + c] / fmaxf((float)(hi - lo), 1.0f);
    __syncthreads();

    float a1 = b1[c];
#pragma unroll 8
    for (int k = 0; k < 64; ++k) a1 = fmaf(hgl[k], W1[k * 64 + c], a1);
    t1[c] = fmaxf(a1, 0.f);
    __syncthreads();

    float a2 = b2[c];
#pragma unroll 8
    for (int k = 0; k < 64; ++k) a2 = fmaf(t1[k], W2[k * 64 + c], a2);
    out[(size_t)g * 64 + c] = a2;
}

extern "C" void kernel_launch(void* const* d_in, const int* in_sizes, int n_in,
                              void* d_out, int out_size, void* d_ws, size_t ws_size,
                              hipStream_t stream) {
    const float* x    = (const float*)d_in[0];
    const int*   src  = (const int*)d_in[1];
    const int*   dst  = (const int*)d_in[2];
    const int*   gid  = (const int*)d_in[3];
    const float* eps0 = (const float*)d_in[4];
    const float* W0a  = (const float*)d_in[5];
    const float* bb0a = (const float*)d_in[6];
    const float* W0b  = (const float*)d_in[7];
    const float* bb0b = (const float*)d_in[8];
    const float* g0i  = (const float*)d_in[9];
    const float* be0i = (const float*)d_in[10];
    const float* m0i  = (const float*)d_in[11];
    const float* v0i  = (const float*)d_in[12];
    const float* g0   = (const float*)d_in[13];
    const float* be0  = (const float*)d_in[14];
    const float* m0   = (const float*)d_in[15];
    const float* v0   = (const float*)d_in[16];
    const float* eps1 = (const float*)d_in[17];
    const float* W1a  = (const float*)d_in[18];
    const float* bb1a = (const float*)d_in[19];
    const float* g1i  = (const float*)d_in[20];
    const float* be1i = (const float*)d_in[21];
    const float* m1i  = (const float*)d_in[22];
    const float* v1i  = (const float*)d_in[23];
    const float* g1   = (const float*)d_in[24];
    const float* be1  = (const float*)d_in[25];
    const float* m1   = (const float*)d_in[26];
    const float* v1   = (const float*)d_in[27];
    const float* Wr1  = (const float*)d_in[28];
    const float* br1  = (const float*)d_in[29];
    const float* Wr2  = (const float*)d_in[30];
    const float* br2  = (const float*)d_in[31];

    const int N = in_sizes[0] / 64;        // 50000
    const int E = in_sizes[1];             // 800000
    const int G = out_size / 64 - N;       // 500
    const int NB = (N + 127) >> 7;         // 391 buckets
    const int EB = (E + EPB - 1) / EPB;    // 391 scatter blocks
    const int CAPB = EB * PER;             // padded bucket capacity

    // ws layout
    char* ws = (char*)d_ws;
    unsigned* xb     = (unsigned*)ws;      ws += (size_t)N * 32 * 4;
    unsigned* Z0b    = (unsigned*)ws;      ws += (size_t)N * 32 * 4;
    int*      rstart = (int*)ws;           ws += ((size_t)N + 8) * 4;
    int*      rend   = (int*)ws;           ws += ((size_t)N + 8) * 4;
    int*      cnts   = (int*)ws;           ws += (size_t)EB * NBP * 4;
    unsigned* ebuf   = (unsigned*)ws;      ws += (size_t)NB * CAPB * 4;
    float*    hg     = (float*)ws;         // G*64 f32 sums

    float* OUT = (float*)d_out;
    float* H   = OUT + (size_t)G * 64;

    const int NQ = N * 8;
    const int NGB = (N + 31) / 32;         // gin_layer blocks

    // ---- build (2 kernels); bucket_fill2 also zeroes hg ----
    cast_scatter<<<EB, 256, 0, stream>>>(
        (uint4*)xb, (const float4*)x, NQ, ebuf, cnts, src, dst, E, NB, CAPB);
    bucket_fill2<<<NB, 256, 0, stream>>>(ebuf, cnts, rstart, rend, hg, G * 64,
                                         N, EB, NB, CAPB);

    // ---- GIN layer 0 (fused aggregate + MLP) ----
    gin_layer<true, true><<<NGB, 512, 0, stream>>>(
        xb, Z0b, nullptr, rstart, rend, ebuf, eps0, N,
        W0a, bb0a, W0b, bb0b, g0i, be0i, m0i, v0i, g0, be0, m0, v0,
        nullptr, nullptr);

    // ---- GIN layer 1 (fused aggregate + MLP + hg accumulation) ----
    gin_layer<false, false><<<NGB, 512, 0, stream>>>(
        Z0b, nullptr, H, rstart, rend, ebuf, eps1, N,
        W1a, bb1a, nullptr, nullptr, g1i, be1i, m1i, v1i, g1, be1, m1, v1,
        gid, hg);

    // ---- tiny readout tail ----
    readout_small<<<G, 64, 0, stream>>>(hg, gid, N, Wr1, br1, Wr2, br2, OUT);
}

// Round 20
// 102.607 us; speedup vs baseline: 1.9572x; 1.9572x over previous
//
#include <hip/hip_runtime.h>

// ---------------------------------------------------------------------------
// GIN forward, bf16 node features. Padded-bucket CSR build + FUSED
// aggregate+MFMA-MLP layers (512-thr / 8-wave blocks, 23KB LDS, 4 blk/CU;
// gather walks TWO nodes per wave concurrently for 2x memory-level
// parallelism — 4-way spills registers, R19) + tiny readout.
// d_out layout: [out (G*64) | h (N*64)]
// ws: [xb | Z0b | rstart | rend | cnts | ebuf | hg]
// Bucket = dst >> 7.  Requires N < 65536 (ids pack u16).
// ---------------------------------------------------------------------------

#define EPB 2048
#define PER 32
#define MAXB 512
#define NBP 512

typedef __attribute__((ext_vector_type(8))) short short8;
typedef __attribute__((ext_vector_type(4))) float f32x4;

__device__ __forceinline__ unsigned bf16pack(float a, float b) {
    unsigned ua = __float_as_uint(a);
    unsigned ub = __float_as_uint(b);
    ua = (ua + 0x7FFFu + ((ua >> 16) & 1u)) >> 16;
    ub = (ub + 0x7FFFu + ((ub >> 16) & 1u)) & 0xFFFF0000u;
    return ua | ub;
}
__device__ __forceinline__ unsigned short bf16r(float a) {
    unsigned u = __float_as_uint(a);
    return (unsigned short)((u + 0x7FFFu + ((u >> 16) & 1u)) >> 16);
}
__device__ __forceinline__ float bf16lo(unsigned w) { return __uint_as_float(w << 16); }
__device__ __forceinline__ float bf16hi(unsigned w) { return __uint_as_float(w & 0xFFFF0000u); }

#define ACC8(A, V)                                       \
    A[0] += bf16lo((V).x); A[1] += bf16hi((V).x);        \
    A[2] += bf16lo((V).y); A[3] += bf16hi((V).y);        \
    A[4] += bf16lo((V).z); A[5] += bf16hi((V).z);        \
    A[6] += bf16lo((V).w); A[7] += bf16hi((V).w);

// ---- K1: cast x->bf16 (grid-strided) + padded-bucket scatter ---------------
__global__ __launch_bounds__(256) void cast_scatter(
    uint4* __restrict__ xb4, const float4* __restrict__ x4, int nq,
    unsigned* __restrict__ ebuf, int* __restrict__ cnts,
    const int* __restrict__ src, const int* __restrict__ dst,
    int E, int NB, int CAPB) {
    __shared__ int h[MAXB];
    const int t = threadIdx.x;
    const int b = blockIdx.x;
    const int nblk = gridDim.x;

    for (int i = b * 256 + t; i < nq; i += nblk * 256) {
        float4 a = x4[2 * i], c = x4[2 * i + 1];
        uint4 o;
        o.x = bf16pack(a.x, a.y); o.y = bf16pack(a.z, a.w);
        o.z = bf16pack(c.x, c.y); o.w = bf16pack(c.z, c.w);
        xb4[i] = o;
    }

    for (int i = t; i < MAXB; i += 256) h[i] = 0;
    __syncthreads();

    const int base = b * EPB;
#pragma unroll
    for (int i = 0; i < 8; ++i) {
        int e = base + i * 256 + t;
        if (e < E) {
            int s = src[e];
            int d = dst[e];
            int k = d >> 7;
            int p = atomicAdd(&h[k], 1);
            if (p < PER)
                ebuf[(size_t)k * CAPB + b * PER + p] =
                    ((unsigned)s << 16) | (unsigned)d;
        }
    }
    __syncthreads();
    for (int i = t; i < NB; i += 256) cnts[(size_t)b * NBP + i] = min(h[i], PER);
}

// ---- K2: compact bucket, rstart/rend + col; also zeroes hg -----------------
__global__ __launch_bounds__(256) void bucket_fill2(
    unsigned* __restrict__ ebuf, const int* __restrict__ cnts,
    int* __restrict__ rstart, int* __restrict__ rend,
    float* __restrict__ hg, int hgn,
    int N, int EB, int NB, int CAPB) {
    __shared__ int tbase[256];
    __shared__ unsigned pairLDS[4608];
    __shared__ unsigned colLDS[4608];
    __shared__ int deg[128], off[128], cur[128];
    const int bb = blockIdx.x;
    const int t = threadIdx.x;
    const int nb0 = bb << 7;
    const int CPT = (EB + 255) / 256;

    for (int i = bb * 256 + t; i < hgn; i += NB * 256) hg[i] = 0.f;

    int myc[8];
    int s = 0;
#pragma unroll 4
    for (int k = 0; k < CPT; ++k) {
        int c = t * CPT + k;
        int v = (c < EB) ? cnts[(size_t)c * NBP + bb] : 0;
        myc[k] = v;
        s += v;
    }
    tbase[t] = s;
    __syncthreads();
    for (int o = 1; o < 256; o <<= 1) {
        int u = (t >= o) ? tbase[t - o] : 0;
        __syncthreads();
        tbase[t] += u;
        __syncthreads();
    }
    const int m = tbase[255];
    int wbase = (t > 0) ? tbase[t - 1] : 0;

#pragma unroll 4
    for (int k = 0; k < CPT; ++k) {
        int c = t * CPT + k;
        int cnt = myc[k];
        for (int j = 0; j < cnt; ++j)
            pairLDS[wbase + j] = ebuf[(size_t)bb * CAPB + c * PER + j];
        wbase += cnt;
    }

    if (t < 128) deg[t] = 0;
    __syncthreads();

    for (int k = t; k < m; k += 256)
        atomicAdd(&deg[(int)(pairLDS[k] & 0xFFFFu) - nb0], 1);
    __syncthreads();
    if (t < 128) off[t] = deg[t];
    __syncthreads();
    for (int s2 = 1; s2 < 128; s2 <<= 1) {
        int u = 0;
        if (t < 128 && t >= s2) u = off[t - s2];
        __syncthreads();
        if (t < 128) off[t] += u;
        __syncthreads();
    }
    if (t < 128) {
        int excl = off[t] - deg[t];
        cur[t] = excl;
        int node = nb0 + t;
        if (node < N) {
            rstart[node] = bb * CAPB + excl;
            rend[node] = bb * CAPB + excl + deg[t];
        }
    }
    __syncthreads();
    for (int k = t; k < m; k += 256) {
        unsigned v = pairLDS[k];
        int dl = (int)(v & 0xFFFFu) - nb0;
        int p = atomicAdd(&cur[dl], 1);
        colLDS[p] = v >> 16;
    }
    __syncthreads();
    for (int k = t; k < m; k += 256) ebuf[(size_t)bb * CAPB + k] = colLDS[k];
}

// ---- FUSED GIN layer: dual-node interleaved gather + MFMA MLP -------------
// 512 threads = 8 waves; block covers 32 rows. Each wave processes its 4
// rows as 2 concurrent pairs (16 neighbor rows in flight). MFMA: wave w
// computes tile (tr=w>>2, tc=w&3), K=64. TWO adds GEMM2; !TWO accumulates
// per-graph sums into hg.
template <bool TWO, bool OUTB>
__global__ __launch_bounds__(512, 8) void gin_layer(
    const unsigned* __restrict__ inb, unsigned* __restrict__ outb,
    float* __restrict__ outf,
    const int* __restrict__ rstart, const int* __restrict__ rend,
    const unsigned* __restrict__ col, const float* __restrict__ eps, int N,
    const float* __restrict__ Wa, const float* __restrict__ ba,
    const float* __restrict__ Wb, const float* __restrict__ bb,
    const float* __restrict__ gi, const float* __restrict__ bei,
    const float* __restrict__ mi, const float* __restrict__ vi,
    const float* __restrict__ go, const float* __restrict__ beo,
    const float* __restrict__ mo, const float* __restrict__ vo,
    const int* __restrict__ gid, float* __restrict__ hg) {
    constexpr int PB = 72;
    __shared__ __align__(16) unsigned short XY[32 * PB];
    __shared__ __align__(16) unsigned short W1t[64 * PB];
    __shared__ __align__(16) unsigned short W2t[TWO ? 64 * PB : 8];
    __shared__ float Yf[TWO ? 1 : 32 * 68];
    __shared__ int gidl[TWO ? 1 : 32];

    const int t = threadIdx.x;
    const int row0 = blockIdx.x * 32;
    const int lane = t & 63;
    const int w = t >> 6;

    // ---- stage weights (f32 [k][c] -> Wt[c][k] bf16) ----
    for (int p = t; p < 1024; p += 512) {
        int k = p >> 4, c4 = (p & 15) * 4;
        float4 v = *reinterpret_cast<const float4*>(&Wa[k * 64 + c4]);
        W1t[(c4 + 0) * PB + k] = bf16r(v.x);
        W1t[(c4 + 1) * PB + k] = bf16r(v.y);
        W1t[(c4 + 2) * PB + k] = bf16r(v.z);
        W1t[(c4 + 3) * PB + k] = bf16r(v.w);
        if (TWO) {
            float4 u = *reinterpret_cast<const float4*>(&Wb[k * 64 + c4]);
            W2t[(c4 + 0) * PB + k] = bf16r(u.x);
            W2t[(c4 + 1) * PB + k] = bf16r(u.y);
            W2t[(c4 + 2) * PB + k] = bf16r(u.z);
            W2t[(c4 + 3) * PB + k] = bf16r(u.w);
        }
    }
    if (!TWO && t < 32) gidl[t] = (row0 + t < N) ? gid[row0 + t] : -1;

    // ---- dual-node interleaved gather-aggregate, bf16 -> XY ----
    {
        const int q = lane & 7;
        const int jj = lane >> 3;
        const uint4* in4 = reinterpret_cast<const uint4*>(inb);
        const float s = 1.0f + eps[0];
#pragma unroll
        for (int itp = 0; itp < 2; ++itp) {
            const int r0 = w * 4 + itp * 2;
            const int r1 = r0 + 1;
            const int n0 = row0 + r0;
            const int n1 = row0 + r1;
            float a0[8], a1[8];
#pragma unroll
            for (int k2 = 0; k2 < 8; ++k2) { a0[k2] = 0.f; a1[k2] = 0.f; }
            int j0 = 0, e0 = 0, j1 = 0, e1 = 0;
            if (n0 < N) { j0 = rstart[n0]; e0 = rend[n0]; }
            if (n1 < N) { j1 = rstart[n1]; e1 = rend[n1]; }
            // interleaved main loops: 16 rows in flight
            while (j0 + 8 <= e0 && j1 + 8 <= e1) {
                unsigned c0 = col[j0 + jj];
                unsigned c1 = col[j1 + jj];
                uint4 v0 = in4[(size_t)c0 * 8 + q];
                uint4 v1 = in4[(size_t)c1 * 8 + q];
                ACC8(a0, v0)
                ACC8(a1, v1)
                j0 += 8; j1 += 8;
            }
            while (j0 + 8 <= e0) {
                unsigned c0 = col[j0 + jj];
                uint4 v0 = in4[(size_t)c0 * 8 + q];
                ACC8(a0, v0)
                j0 += 8;
            }
            while (j1 + 8 <= e1) {
                unsigned c1 = col[j1 + jj];
                uint4 v1 = in4[(size_t)c1 * 8 + q];
                ACC8(a1, v1)
                j1 += 8;
            }
            if (j0 + jj < e0) {
                unsigned c0 = col[j0 + jj];
                uint4 v0 = in4[(size_t)c0 * 8 + q];
                ACC8(a0, v0)
            }
            if (j1 + jj < e1) {
                unsigned c1 = col[j1 + jj];
                uint4 v1 = in4[(size_t)c1 * 8 + q];
                ACC8(a1, v1)
            }
#pragma unroll
            for (int k2 = 0; k2 < 8; ++k2) {
                a0[k2] += __shfl_xor(a0[k2], 8);
                a1[k2] += __shfl_xor(a1[k2], 8);
                a0[k2] += __shfl_xor(a0[k2], 16);
                a1[k2] += __shfl_xor(a1[k2], 16);
                a0[k2] += __shfl_xor(a0[k2], 32);
                a1[k2] += __shfl_xor(a1[k2], 32);
            }
            if (jj == 0) {
                if (n0 < N) {
                    uint4 o = in4[(size_t)n0 * 8 + q];
                    a0[0] = fmaf(s, bf16lo(o.x), a0[0]);
                    a0[1] = fmaf(s, bf16hi(o.x), a0[1]);
                    a0[2] = fmaf(s, bf16lo(o.y), a0[2]);
                    a0[3] = fmaf(s, bf16hi(o.y), a0[3]);
                    a0[4] = fmaf(s, bf16lo(o.z), a0[4]);
                    a0[5] = fmaf(s, bf16hi(o.z), a0[5]);
                    a0[6] = fmaf(s, bf16lo(o.w), a0[6]);
                    a0[7] = fmaf(s, bf16hi(o.w), a0[7]);
                }
                uint4 wv;
                wv.x = bf16pack(a0[0], a0[1]); wv.y = bf16pack(a0[2], a0[3]);
                wv.z = bf16pack(a0[4], a0[5]); wv.w = bf16pack(a0[6], a0[7]);
                *reinterpret_cast<uint4*>(&XY[r0 * PB + q * 8]) = wv;
                if (n1 < N) {
                    uint4 o = in4[(size_t)n1 * 8 + q];
                    a1[0] = fmaf(s, bf16lo(o.x), a1[0]);
                    a1[1] = fmaf(s, bf16hi(o.x), a1[1]);
                    a1[2] = fmaf(s, bf16lo(o.y), a1[2]);
                    a1[3] = fmaf(s, bf16hi(o.y), a1[3]);
                    a1[4] = fmaf(s, bf16lo(o.z), a1[4]);
                    a1[5] = fmaf(s, bf16hi(o.z), a1[5]);
                    a1[6] = fmaf(s, bf16lo(o.w), a1[6]);
                    a1[7] = fmaf(s, bf16hi(o.w), a1[7]);
                }
                wv.x = bf16pack(a1[0], a1[1]); wv.y = bf16pack(a1[2], a1[3]);
                wv.z = bf16pack(a1[4], a1[5]); wv.w = bf16pack(a1[6], a1[7]);
                *reinterpret_cast<uint4*>(&XY[r1 * PB + q * 8]) = wv;
            }
        }
    }
    __syncthreads();

    // ---- GEMM1: wave w -> tile (tr=w>>2, tc=w&3) ----
    const int cl = lane & 15;
    const int kg = lane >> 4;
    const int tr = w >> 2;
    const int tc = w & 3;
    const int arow = tr * 16 + cl;
    const int bcol = tc * 16 + cl;
    const int rowb = tr * 16 + kg * 4;
    const int c = tc * 16 + cl;

    f32x4 acc = (f32x4){0.f, 0.f, 0.f, 0.f};
#pragma unroll
    for (int kk = 0; kk < 64; kk += 32) {
        short8 af = *reinterpret_cast<const short8*>(&XY[arow * PB + kk + kg * 8]);
        short8 bf = *reinterpret_cast<const short8*>(&W1t[bcol * PB + kk + kg * 8]);
        acc = __builtin_amdgcn_mfma_f32_16x16x32_bf16(af, bf, acc, 0, 0, 0);
    }

    if (TWO) {
        __syncthreads();
        {
            float bias = ba[c];
#pragma unroll
            for (int r = 0; r < 4; ++r)
                XY[(rowb + r) * PB + c] = bf16r(fmaxf(acc[r] + bias, 0.f));
        }
        __syncthreads();
        acc = (f32x4){0.f, 0.f, 0.f, 0.f};
#pragma unroll
        for (int kk = 0; kk < 64; kk += 32) {
            short8 af = *reinterpret_cast<const short8*>(&XY[arow * PB + kk + kg * 8]);
            short8 bf = *reinterpret_cast<const short8*>(&W2t[bcol * PB + kk + kg * 8]);
            acc = __builtin_amdgcn_mfma_f32_16x16x32_bf16(af, bf, acc, 0, 0, 0);
        }
    }

    // ---- epilogue: bias + relu + fused double-BN + relu + store ----
    {
        const float* bias2 = TWO ? bb : ba;
        float si = gi[c] * rsqrtf(vi[c] + 1e-5f);
        float ti = bei[c] - mi[c] * si;
        float so = go[c] * rsqrtf(vo[c] + 1e-5f);
        float to = beo[c] - mo[c] * so;
        float scv = si * so;
        float shv = ti * so + to;
        float bias = bias2[c];
#pragma unroll
        for (int r = 0; r < 4; ++r) {
            int grow = row0 + rowb + r;
            float y = 0.f;
            if (grow < N) {
                float u = fmaxf(acc[r] + bias, 0.f);
                y = fmaxf(u * scv + shv, 0.f);
                if (OUTB) {
                    reinterpret_cast<unsigned short*>(outb)[(size_t)grow * 64 + c] =
                        bf16r(y);
                } else {
                    outf[(size_t)grow * 64 + c] = y;
                }
            }
            if (!TWO) Yf[(rowb + r) * 68 + c] = y;
        }
    }

    if (!TWO) {
        __syncthreads();
        if (t < 64) {
            const int cc = t;
            float run = 0.f;
            int cg = -2;
            for (int r = 0; r < 32; ++r) {
                int rg = gidl[r];
                if (rg != cg) {
                    if (cg >= 0) atomicAdd(&hg[(size_t)cg * 64 + cc], run);
                    run = 0.f;
                    cg = rg;
                }
                if (rg >= 0) run += Yf[r * 68 + cc];
            }
            if (cg >= 0) atomicAdd(&hg[(size_t)cg * 64 + cc], run);
        }
    }
}

__device__ __forceinline__ int lbound(const int* __restrict__ a, int n, int v) {
    int lo = 0, hi = n;
    while (lo < hi) {
        int mid = (lo + hi) >> 1;
        if (a[mid] < v) lo = mid + 1;
        else hi = mid;
    }
    return lo;
}

// ---- tiny readout: out = relu(hg/cnt @ W1 + b1) @ W2 + b2 ------------------
__global__ __launch_bounds__(64) void readout_small(
    const float* __restrict__ hg, const int* __restrict__ gid, int N,
    const float* __restrict__ W1, const float* __restrict__ b1,
    const float* __restrict__ W2, const float* __restrict__ b2,
    float* __restrict__ out) {
    __shared__ float hgl[64];
    __shared__ float t1[64];
    const int g = blockIdx.x;
    const int c = threadIdx.x;

    const int lo = lbound(gid, N, g);
    const int hi = lbound(gid, N, g + 1);
    hgl[c] = hg[(size_t)g * 64 + c] / fmaxf((float)(hi - lo), 1.0f);
    __syncthreads();

    float a1 = b1[c];
#pragma unroll 8
    for (int k = 0; k < 64; ++k) a1 = fmaf(hgl[k], W1[k * 64 + c], a1);
    t1[c] = fmaxf(a1, 0.f);
    __syncthreads();

    float a2 = b2[c];
#pragma unroll 8
    for (int k = 0; k < 64; ++k) a2 = fmaf(t1[k], W2[k * 64 + c], a2);
    out[(size_t)g * 64 + c] = a2;
}

extern "C" void kernel_launch(void* const* d_in, const int* in_sizes, int n_in,
                              void* d_out, int out_size, void* d_ws, size_t ws_size,
                              hipStream_t stream) {
    const float* x    = (const float*)d_in[0];
    const int*   src  = (const int*)d_in[1];
    const int*   dst  = (const int*)d_in[2];
    const int*   gid  = (const int*)d_in[3];
    const float* eps0 = (const float*)d_in[4];
    const float* W0a  = (const float*)d_in[5];
    const float* bb0a = (const float*)d_in[6];
    const float* W0b  = (const float*)d_in[7];
    const float* bb0b = (const float*)d_in[8];
    const float* g0i  = (const float*)d_in[9];
    const float* be0i = (const float*)d_in[10];
    const float* m0i  = (const float*)d_in[11];
    const float* v0i  = (const float*)d_in[12];
    const float* g0   = (const float*)d_in[13];
    const float* be0  = (const float*)d_in[14];
    const float* m0   = (const float*)d_in[15];
    const float* v0   = (const float*)d_in[16];
    const float* eps1 = (const float*)d_in[17];
    const float* W1a  = (const float*)d_in[18];
    const float* bb1a = (const float*)d_in[19];
    const float* g1i  = (const float*)d_in[20];
    const float* be1i = (const float*)d_in[21];
    const float* m1i  = (const float*)d_in[22];
    const float* v1i  = (const float*)d_in[23];
    const float* g1   = (const float*)d_in[24];
    const float* be1  = (const float*)d_in[25];
    const float* m1   = (const float*)d_in[26];
    const float* v1   = (const float*)d_in[27];
    const float* Wr1  = (const float*)d_in[28];
    const float* br1  = (const float*)d_in[29];
    const float* Wr2  = (const float*)d_in[30];
    const float* br2  = (const float*)d_in[31];

    const int N = in_sizes[0] / 64;        // 50000
    const int E = in_sizes[1];             // 800000
    const int G = out_size / 64 - N;       // 500
    const int NB = (N + 127) >> 7;         // 391 buckets
    const int EB = (E + EPB - 1) / EPB;    // 391 scatter blocks
    const int CAPB = EB * PER;             // padded bucket capacity

    // ws layout
    char* ws = (char*)d_ws;
    unsigned* xb     = (unsigned*)ws;      ws += (size_t)N * 32 * 4;
    unsigned* Z0b    = (unsigned*)ws;      ws += (size_t)N * 32 * 4;
    int*      rstart = (int*)ws;           ws += ((size_t)N + 8) * 4;
    int*      rend   = (int*)ws;           ws += ((size_t)N + 8) * 4;
    int*      cnts   = (int*)ws;           ws += (size_t)EB * NBP * 4;
    unsigned* ebuf   = (unsigned*)ws;      ws += (size_t)NB * CAPB * 4;
    float*    hg     = (float*)ws;         // G*64 f32 sums

    float* OUT = (float*)d_out;
    float* H   = OUT + (size_t)G * 64;

    const int NQ = N * 8;
    const int NGB = (N + 31) / 32;         // gin_layer blocks

    // ---- build (2 kernels); bucket_fill2 also zeroes hg ----
    cast_scatter<<<EB, 256, 0, stream>>>(
        (uint4*)xb, (const float4*)x, NQ, ebuf, cnts, src, dst, E, NB, CAPB);
    bucket_fill2<<<NB, 256, 0, stream>>>(ebuf, cnts, rstart, rend, hg, G * 64,
                                         N, EB, NB, CAPB);

    // ---- GIN layer 0 (fused aggregate + MLP) ----
    gin_layer<true, true><<<NGB, 512, 0, stream>>>(
        xb, Z0b, nullptr, rstart, rend, ebuf, eps0, N,
        W0a, bb0a, W0b, bb0b, g0i, be0i, m0i, v0i, g0, be0, m0, v0,
        nullptr, nullptr);

    // ---- GIN layer 1 (fused aggregate + MLP + hg accumulation) ----
    gin_layer<false, false><<<NGB, 512, 0, stream>>>(
        Z0b, nullptr, H, rstart, rend, ebuf, eps1, N,
        W1a, bb1a, nullptr, nullptr, g1i, be1i, m1i, v1i, g1, be1, m1, v1,
        gid, hg);

    // ---- tiny readout tail ----
    readout_small<<<G, 64, 0, stream>>>(hg, gid, N, Wr1, br1, Wr2, br2, OUT);
}